// Round 7
// baseline (20.799 us; speedup 1.0000x reference)
//
#include <hip/hip_runtime.h>
#include <stdint.h>

#define THREADS 256
#define BOARDS_PER_BLOCK 256   // 1 board per thread
#define STRIDE_DW 13           // 52 B/board in LDS; odd dword stride -> conflict-free reads

typedef float f32x4 __attribute__((ext_vector_type(4)));  // native vec for nt-load

// Column-range mask in 7-wide layout: bit = 7*r + c, r=0 top .. 5 bottom.
static constexpr uint64_t colmask(int lo, int hi) {
    uint64_t m = 0;
    for (int r = 0; r < 6; ++r)
        for (int c = lo; c <= hi; ++c)
            m |= 1ull << (7 * r + c);
    return m;
}

// Cells where placing a piece of `P`'s color completes 4-in-a-row.
// 7-wide layout; column-wrap handled by per-term column masks.
static __device__ __forceinline__ uint64_t win_cells(uint64_t P) {
    uint64_t w = 0;
    #pragma unroll
    for (int d = 0; d < 4; ++d) {
        const int s  = (d == 0) ? 1 : (d == 1) ? 7 : (d == 2) ? 8 : 6;
        const int dc = (d == 0) ? 1 : (d == 1) ? 0 : (d == 2) ? 1 : -1;
        const uint64_t M0 = (dc == 0) ? ~0ull : (dc > 0 ? colmask(0, 3) : colmask(3, 6));
        const uint64_t M1 = (dc == 0) ? ~0ull : (dc > 0 ? colmask(1, 4) : colmask(2, 5));
        const uint64_t M2 = (dc == 0) ? ~0ull : (dc > 0 ? colmask(2, 5) : colmask(1, 4));
        const uint64_t M3 = (dc == 0) ? ~0ull : (dc > 0 ? colmask(3, 6) : colmask(0, 3));
        uint64_t r1 = P >> s, r2 = P >> (2 * s), r3 = P >> (3 * s);
        uint64_t l1 = P << s, l2 = P << (2 * s), l3 = P << (3 * s);
        uint64_t u = r1 & r2, v = l1 & l2;
        w |= (u & r3 & M0) | (u & l1 & M1) | (v & r1 & M2) | (v & l3 & M3);
    }
    return w;
}

// OR all 6 rows (period 7) into the low 7 bits.
static __device__ __forceinline__ uint32_t colfold(uint64_t v) {
    v |= v >> 21;
    v |= v >> 7;
    v |= v >> 7;
    return (uint32_t)v & 0x7Fu;
}

extern "C" __global__ void __launch_bounds__(THREADS, 8)
c4_kernel(const float* __restrict__ x, float* __restrict__ out)
{
    // 256 boards x 52 B packed cells; later reused as the 7168 B output stage.
    __shared__ uint32_t s_mem[BOARDS_PER_BLOCK * STRIDE_DW];   // 13312 B
    uint16_t* s16   = reinterpret_cast<uint16_t*>(s_mem);
    float*    s_out = reinterpret_cast<float*>(s_mem);

    const int tid = threadIdx.x;
    const size_t board0 = (size_t)blockIdx.x * BOARDS_PER_BLOCK;

    // ---- coalesced nt global -> LDS: cell -> top byte, 52 B/board stride ----
    // bit5 (0x20): occupied (0x3f / 0xbf), bit7 (0x80): cell is -1 (0xbf)
    const f32x4* src = reinterpret_cast<const f32x4*>(x) + (size_t)blockIdx.x * 2688u;
    #pragma unroll
    for (int k = 0; k < 11; ++k) {
        int n = k * THREADS + tid;              // 2688 float4 per block, last iter half
        if (n < 2688) {
            f32x4 v = __builtin_nontemporal_load(&src[n]);
            uint32_t a = __float_as_uint(v.x), b = __float_as_uint(v.y),
                     c = __float_as_uint(v.z), d = __float_as_uint(v.w);
            uint32_t u01 = __builtin_amdgcn_perm(b, a, 0x00000703u); // [top(a),top(b)]
            uint32_t u23 = __builtin_amdgcn_perm(d, c, 0x00000703u); // [top(c),top(d)]
            uint32_t c0 = 4u * (uint32_t)n;
            uint32_t b0 = (c0 * 24967u) >> 20;  uint32_t i0 = c0 - 42u * b0;
            uint32_t c2 = c0 + 2u;
            uint32_t b2 = (c2 * 24967u) >> 20;  uint32_t i2 = c2 - 42u * b2;
            s16[26u * b0 + (i0 >> 1)] = (uint16_t)u01;   // cells c0, c0+1
            s16[26u * b2 + (i2 >> 1)] = (uint16_t)u23;   // cells c0+2, c0+3
        }
    }
    __syncthreads();

    // ---- per-thread: own board = 11 dwords at conflict-free stride 13 ----
    const uint32_t* pk = s_mem + tid * STRIDE_DW;
    uint32_t occ_lo = 0, occ_hi = 0, mm_lo = 0, mm_hi = 0;
    #pragma unroll
    for (int j = 0; j < 11; ++j) {
        uint32_t e = pk[j];
        uint32_t nO = ((e & 0x20202020u) * 0x00204081u) >> 26;  // occupied nibble
        uint32_t nM = ((e & 0x80808080u) * 0x00204081u) >> 28;  // minus nibble
        if (j == 10) { nO &= 3u; nM &= 3u; }    // bytes 42..43 are pad
        if (j < 8) { occ_lo |= nO << (4 * j);      mm_lo |= nM << (4 * j); }
        else       { occ_hi |= nO << (4 * j - 32); mm_hi |= nM << (4 * j - 32); }
    }
    uint64_t o = (uint64_t)occ_lo | ((uint64_t)occ_hi << 32);
    uint64_t m = (uint64_t)mm_lo  | ((uint64_t)mm_hi  << 32);
    uint64_t p = o & ~m;

    const uint64_t ROW5 = 0x7Full << 35;        // bottom row
    uint64_t land = ~o & ((o >> 7) | ROW5);     // landing cell per column

    uint32_t cp = colfold(land & win_cells(p)); // +1 winning columns
    uint32_t cm = colfold(land & win_cells(m)); // -1 winning columns
    uint32_t sel = cp ? cp : cm;                // +1 takes precedence
    bool any = (sel != 0u);
    int col  = __ffs(sel) - 1;                  // lowest winning column

    __syncthreads();                            // all LDS reads done before reuse

    float* so = s_out + tid * 7;
    #pragma unroll
    for (int c = 0; c < 7; ++c)
        so[c] = (any && c != col) ? -27.631021f : 0.0f;
    __syncthreads();

    // ---- coalesced nt LDS -> global: 1792 floats per block ----
    float* dst = out + board0 * 7u;
    #pragma unroll
    for (int k = 0; k < 7; ++k) {
        int n = k * THREADS + tid;
        __builtin_nontemporal_store(s_out[n], &dst[n]);
    }
}

extern "C" void kernel_launch(void* const* d_in, const int* in_sizes, int n_in,
                              void* d_out, int out_size, void* d_ws, size_t ws_size,
                              hipStream_t stream)
{
    const float* x = (const float*)d_in[0];
    float* out = (float*)d_out;
    const int N = in_sizes[0] / 42;                 // 524288 boards
    const int grid = N / BOARDS_PER_BLOCK;          // 2048 blocks = 8 per CU
    hipLaunchKernelGGL(c4_kernel, dim3(grid), dim3(THREADS), 0, stream, x, out);
}

// Round 8
// 19.618 us; speedup vs baseline: 1.0602x; 1.0602x over previous
//
#include <hip/hip_runtime.h>
#include <stdint.h>

#define THREADS 256
#define BOARDS_PER_BLOCK 512   // 2 boards per thread, 4 waves per block

typedef float f32x4 __attribute__((ext_vector_type(4)));  // native vec for nt-load

// Column-range mask in 7-wide layout: bit = 7*r + c, r=0 top .. 5 bottom.
static constexpr uint64_t colmask(int lo, int hi) {
    uint64_t m = 0;
    for (int r = 0; r < 6; ++r)
        for (int c = lo; c <= hi; ++c)
            m |= 1ull << (7 * r + c);
    return m;
}

// Cells where placing a piece of `P`'s color completes 4-in-a-row.
// 7-wide layout; column-wrap handled by per-term column masks.
static __device__ __forceinline__ uint64_t win_cells(uint64_t P) {
    uint64_t w = 0;
    #pragma unroll
    for (int d = 0; d < 4; ++d) {
        const int s  = (d == 0) ? 1 : (d == 1) ? 7 : (d == 2) ? 8 : 6;
        const int dc = (d == 0) ? 1 : (d == 1) ? 0 : (d == 2) ? 1 : -1;
        const uint64_t M0 = (dc == 0) ? ~0ull : (dc > 0 ? colmask(0, 3) : colmask(3, 6));
        const uint64_t M1 = (dc == 0) ? ~0ull : (dc > 0 ? colmask(1, 4) : colmask(2, 5));
        const uint64_t M2 = (dc == 0) ? ~0ull : (dc > 0 ? colmask(2, 5) : colmask(1, 4));
        const uint64_t M3 = (dc == 0) ? ~0ull : (dc > 0 ? colmask(3, 6) : colmask(0, 3));
        uint64_t r1 = P >> s, r2 = P >> (2 * s), r3 = P >> (3 * s);
        uint64_t l1 = P << s, l2 = P << (2 * s), l3 = P << (3 * s);
        uint64_t u = r1 & r2, v = l1 & l2;
        w |= (u & r3 & M0) | (u & l1 & M1) | (v & r1 & M2) | (v & l3 & M3);
    }
    return w;
}

// OR all 6 rows (period 7) into the low 7 bits.
static __device__ __forceinline__ uint32_t colfold(uint64_t v) {
    v |= v >> 21;
    v |= v >> 7;
    v |= v >> 7;
    return (uint32_t)v & 0x7Fu;
}

extern "C" __global__ void __launch_bounds__(THREADS)
c4_kernel(const float* __restrict__ x, float* __restrict__ out)
{
    // 512 boards x 42 packed cell-bytes = 21504 B; output stage aliases it.
    __shared__ uint32_t s_mem[BOARDS_PER_BLOCK * 42 / 4];  // 5376 dwords
    float* s_out = reinterpret_cast<float*>(s_mem);        // 3584 floats (14336 B)

    const int tid = threadIdx.x;
    const size_t board0 = (size_t)blockIdx.x * BOARDS_PER_BLOCK;

    // ---- coalesced nt global -> LDS, each cell compressed to its top byte ----
    // bit5 (0x20): occupied (0x3f / 0xbf), bit7 (0x80): cell is -1 (0xbf)
    const f32x4* src = reinterpret_cast<const f32x4*>(x) + (size_t)blockIdx.x * 5376u;
    #pragma unroll
    for (int k = 0; k < 21; ++k) {
        int n = k * THREADS + tid;              // lane-consecutive 16B loads
        f32x4 v = __builtin_nontemporal_load(&src[n]);
        uint32_t a = __float_as_uint(v.x), b = __float_as_uint(v.y),
                 c = __float_as_uint(v.z), d = __float_as_uint(v.w);
        uint32_t u01 = __builtin_amdgcn_perm(b, a, 0x00000703u);   // [top a, top b]
        uint32_t u23 = __builtin_amdgcn_perm(d, c, 0x00000703u);   // [top c, top d]
        s_mem[n] = __builtin_amdgcn_perm(u23, u01, 0x05040100u);   // 3-op pack
    }
    __syncthreads();

    // ---- per-thread: 21 dwords = 2 boards' 84 cell-bytes (stride 21: no conflicts) ----
    const uint32_t* pk = s_mem + tid * 21;
    uint64_t occ[2] = {0, 0}, MM[2] = {0, 0};
    #pragma unroll
    for (int j = 0; j < 21; ++j) {
        uint32_t e = pk[j];
        uint32_t nO = ((e & 0x20202020u) * 0x00204081u) >> 26;  // occupied
        uint32_t nM = ((e & 0x80808080u) * 0x00204081u) >> 28;  // minus
        if (j < 10) {
            occ[0] |= (uint64_t)nO << (4 * j);
            MM[0]  |= (uint64_t)nM << (4 * j);
        } else if (j == 10) {                   // cells 40,41 | 42,43 straddle
            occ[0] |= (uint64_t)(nO & 3u) << 40;
            MM[0]  |= (uint64_t)(nM & 3u) << 40;
            occ[1] |= (uint64_t)(nO >> 2);
            MM[1]  |= (uint64_t)(nM >> 2);
        } else {
            occ[1] |= (uint64_t)nO << (4 * j - 42);
            MM[1]  |= (uint64_t)nM << (4 * j - 42);
        }
    }

    float vals[14];
    #pragma unroll
    for (int b = 0; b < 2; ++b) {
        uint64_t o = occ[b], m = MM[b], p = o & ~m;
        const uint64_t ROW5 = 0x7Full << 35;    // bottom row
        uint64_t land = ~o & ((o >> 7) | ROW5); // landing cell per column

        uint32_t cp = colfold(land & win_cells(p));  // +1 winning columns
        uint32_t cm = colfold(land & win_cells(m));  // -1 winning columns
        uint32_t sel = cp ? cp : cm;                 // +1 takes precedence
        bool any = (sel != 0u);
        int col  = __ffs(sel) - 1;                   // lowest winning column

        #pragma unroll
        for (int c = 0; c < 7; ++c)
            vals[7 * b + c] = (any && c != col) ? -27.631021f : 0.0f;
    }
    __syncthreads();                            // all s_mem reads done before alias-write

    float* so = s_out + tid * 14;
    #pragma unroll
    for (int i = 0; i < 14; ++i)
        so[i] = vals[i];
    __syncthreads();

    // ---- coalesced nt LDS -> global: 3584 floats per block ----
    float* dst = out + board0 * 7u;
    #pragma unroll
    for (int k = 0; k < 14; ++k) {
        int n = k * THREADS + tid;
        __builtin_nontemporal_store(s_out[n], &dst[n]);
    }
}

extern "C" void kernel_launch(void* const* d_in, const int* in_sizes, int n_in,
                              void* d_out, int out_size, void* d_ws, size_t ws_size,
                              hipStream_t stream)
{
    const float* x = (const float*)d_in[0];
    float* out = (float*)d_out;
    const int N = in_sizes[0] / 42;                 // 524288 boards
    const int grid = N / BOARDS_PER_BLOCK;          // 1024 blocks = 4 per CU, 1 round
    hipLaunchKernelGGL(c4_kernel, dim3(grid), dim3(THREADS), 0, stream, x, out);
}